// Round 1
// 314.681 us; speedup vs baseline: 1.1274x; 1.1274x over previous
//
#include <hip/hip_runtime.h>

// Problem constants (from reference setup_inputs):
//   x:   [B=8, C=16, H=512, W=512] float32
//   phi: [B=8, 2,    H=512, W=512] float32  (dy = phi[:,0], dx = phi[:,1])
//   out: [B, C, H, W] float32
// Bilinear pull with wrap (circulant) boundary. H, W powers of two -> mod == & (N-1).
//
// Strategy (v2): the previous single-pass kernel was L1/TA scatter-throughput
// bound (64 divergent 4B loads/thread; VALUBusy 6.8%, HBM 29%). We stage x
// channels-last in workspace ([B,HW,16] floats = one aligned 64B line per
// pixel), then gather with 4 threads per output pixel (one channel-quad each)
// so the 4 lanes of a pixel read the 4 quarters of the SAME 64B line via
// dwordx4 -> every gathered line is fully consumed, load instrs/thread 64->4.

constexpr int B = 8, C = 16, H = 512, W = 512;
constexpr int HW = H * W;

// ---------------- pass 1: x [B,C,HW] -> xt [B,HW,C] (channels-last) --------
__global__ __launch_bounds__(256) void transpose_kernel(const float* __restrict__ x,
                                                        float4* __restrict__ xt4) {
    int idx = blockIdx.x * blockDim.x + threadIdx.x;   // over B*HW*4 (exact)
    int b   = idx >> 20;                               // / (HW*4)
    int rem = idx & (HW * 4 - 1);
    int p   = rem >> 2;                                // pixel within plane
    int q   = rem & 3;                                 // channel quad 0..3

    // read 4 channels (q*4 .. q*4+3) of pixel p: 4 coalesced dword loads
    const float* src = x + ((size_t)b * C + q * 4) * HW + p;
    float4 v;
    v.x = src[0];
    v.y = src[(size_t)HW];
    v.z = src[(size_t)2 * HW];
    v.w = src[(size_t)3 * HW];
    // write: consecutive lanes -> consecutive float4 -> contiguous 1KB/wave
    xt4[((size_t)b * HW + p) * 4 + q] = v;
}

// ---------------- pass 2: vectorized gather --------------------------------
__global__ __launch_bounds__(256) void gather_kernel(const float4* __restrict__ xt4,
                                                     const float* __restrict__ phi,
                                                     float* __restrict__ out) {
    int idx = blockIdx.x * blockDim.x + threadIdx.x;   // over B*HW*4 (exact)
    int b   = idx >> 20;
    int rem = idx & (HW * 4 - 1);
    int p   = rem >> 2;                                // output pixel
    int q   = rem & 3;                                 // channel quad
    int h   = p >> 9;
    int w   = p & (W - 1);

    const float* phib = phi + (size_t)b * 2 * HW;
    float cy = phib[p]      + (float)h;                // broadcast within 4-lane group
    float cx = phib[HW + p] + (float)w;

    float y0f = floorf(cy);
    float x0f = floorf(cx);
    float wy  = cy - y0f;
    float wx  = cx - x0f;

    int y0 = ((int)y0f) & (H - 1);
    int x0 = ((int)x0f) & (W - 1);
    int y1 = (y0 + 1)   & (H - 1);
    int x1 = (x0 + 1)   & (W - 1);

    const float4* base = xt4 + (size_t)b * HW * 4;
    // 4 lanes (q=0..3) of one pixel cover the 4 quarters of each 64B line
    float4 v00 = base[(y0 * W + x0) * 4 + q];
    float4 v01 = base[(y0 * W + x1) * 4 + q];
    float4 v10 = base[(y1 * W + x0) * 4 + q];
    float4 v11 = base[(y1 * W + x1) * 4 + q];

    float omwx = 1.0f - wx;
    float omwy = 1.0f - wy;

    float4 r;
    r.x = (v00.x * omwx + v01.x * wx) * omwy + (v10.x * omwx + v11.x * wx) * wy;
    r.y = (v00.y * omwx + v01.y * wx) * omwy + (v10.y * omwx + v11.y * wx) * wy;
    r.z = (v00.z * omwx + v01.z * wx) * omwy + (v10.z * omwx + v11.z * wx) * wy;
    r.w = (v00.w * omwx + v01.w * wx) * omwy + (v10.w * omwx + v11.w * wx) * wy;

    // out[b][q*4+j][h][w]; per store-instr lanes form 4 fully-consumed
    // 64B segments (one per q) -> coalesced enough, all bytes written
    float* outp = out + ((size_t)b * C + q * 4) * HW + p;
    outp[0]              = r.x;
    outp[(size_t)HW]     = r.y;
    outp[(size_t)2 * HW] = r.z;
    outp[(size_t)3 * HW] = r.w;
}

// ---------------- fallback: previous best single-pass kernel ---------------
__global__ __launch_bounds__(256) void pull_wrap_kernel(const float* __restrict__ x,
                                                        const float* __restrict__ phi,
                                                        float* __restrict__ out) {
    int idx = blockIdx.x * blockDim.x + threadIdx.x;  // over B*H*W
    if (idx >= B * HW) return;
    int b  = idx >> 18;
    int hw = idx & (HW - 1);
    int h  = hw >> 9;
    int w  = hw & (W - 1);

    const float* phib = phi + (size_t)b * 2 * HW;
    float cy = phib[hw]      + (float)h;
    float cx = phib[HW + hw] + (float)w;

    float y0f = floorf(cy);
    float x0f = floorf(cx);
    float wy  = cy - y0f;
    float wx  = cx - x0f;

    int y0 = ((int)y0f) & (H - 1);
    int x0 = ((int)x0f) & (W - 1);
    int y1 = (y0 + 1)   & (H - 1);
    int x1 = (x0 + 1)   & (W - 1);

    int o00 = y0 * W + x0;
    int o01 = y0 * W + x1;
    int o10 = y1 * W + x0;
    int o11 = y1 * W + x1;

    float omwx = 1.0f - wx;
    float omwy = 1.0f - wy;

    const float* plane = x   + (size_t)b * C * HW;
    float*       outp  = out + (size_t)b * C * HW + hw;

#pragma unroll
    for (int c = 0; c < C; ++c) {
        float v00 = plane[o00];
        float v01 = plane[o01];
        float v10 = plane[o10];
        float v11 = plane[o11];
        float top = v00 * omwx + v01 * wx;
        float bot = v10 * omwx + v11 * wx;
        outp[(size_t)c * HW] = top * omwy + bot * wy;
        plane += HW;
    }
}

extern "C" void kernel_launch(void* const* d_in, const int* in_sizes, int n_in,
                              void* d_out, int out_size, void* d_ws, size_t ws_size,
                              hipStream_t stream) {
    const float* x   = (const float*)d_in[0];
    const float* phi = (const float*)d_in[1];
    float* out = (float*)d_out;

    size_t need = (size_t)B * C * HW * sizeof(float);  // 128 MiB channels-last copy
    if (d_ws != nullptr && ws_size >= need) {
        int n = B * HW * 4;                 // 4 threads (channel quads) per pixel
        dim3 block(256);
        dim3 grid(n / 256);                 // exact multiple
        transpose_kernel<<<grid, block, 0, stream>>>(x, (float4*)d_ws);
        gather_kernel<<<grid, block, 0, stream>>>((const float4*)d_ws, phi, out);
    } else {
        int n = B * HW;
        dim3 block(256);
        dim3 grid((n + 255) / 256);
        pull_wrap_kernel<<<grid, block, 0, stream>>>(x, phi, out);
    }
}